// Round 3
// baseline (1398.375 us; speedup 1.0000x reference)
//
#include <hip/hip_runtime.h>
#include <hip/hip_bf16.h>
#include <math.h>

#define VOCAB 50257
#define NCLS 20
#define EDIM 64
#define HDIM 64
#define BATCH 128
#define TLEN 2048

typedef float v2f __attribute__((ext_vector_type(2)));

// Static device scratch: no dependence on ws_size, graph-capture safe.
__device__ float g_P[(size_t)2 * VOCAB * 192];   // 77.2 MB, input-projected vocab table (bias folded)
__device__ float g_feats[BATCH * 256];           // pooled features

__device__ __forceinline__ float fast_rcp(float x) { return __builtin_amdgcn_rcpf(x); }

__device__ __forceinline__ float fsigmoid(float x) {
    // 1/(1+exp(-x)); saturates correctly at +-inf
    return fast_rcp(1.f + __expf(-x));
}
__device__ __forceinline__ float ftanh(float x) {
    // 1 - 2/(exp(2x)+1); saturates correctly at +-inf
    float e = __expf(2.f * x);
    return 1.f - 2.f * fast_rcp(e + 1.f);
}

// ---------------- Kernel A: P[dir][v][g] = dot(emb[v], wih[dir][g]) + bih[dir][g] ----------------
// 2-way v-unroll: two independent 64-deep FMA chains per iteration (ILP vs the 4-cyc dep latency).
__global__ __launch_bounds__(384) void precompute_P(
    const float* __restrict__ emb,
    const float* __restrict__ wih_f, const float* __restrict__ bih_f,
    const float* __restrict__ wih_b, const float* __restrict__ bih_b)
{
    const int t = threadIdx.x;          // 0..383 ; waves are uniform in (dir), contiguous in g
    const int dir = t / 192;
    const int g = t % 192;
    const float* wih = dir ? wih_b : wih_f;
    const float* bih = dir ? bih_b : bih_f;

    float w[64];
#pragma unroll
    for (int e = 0; e < 64; e += 4) {
        float4 v = *(const float4*)(wih + (size_t)g * 64 + e);
        w[e] = v.x; w[e + 1] = v.y; w[e + 2] = v.z; w[e + 3] = v.w;
    }
    const float bias = bih[g];
    float* Pd = g_P + (size_t)dir * VOCAB * 192;

    for (int v = blockIdx.x * 2; v < VOCAB; v += gridDim.x * 2) {
        const int v1ok = (v + 1 < VOCAB);
        const float4* e0 = (const float4*)(emb + (size_t)v * 64);            // wave-uniform -> scalar loads
        const float4* e1 = (const float4*)(emb + (size_t)(v1ok ? v + 1 : v) * 64);
        float a0 = bias, a1 = bias;
#pragma unroll
        for (int e4 = 0; e4 < 16; e4++) {
            float4 x = e0[e4];
            float4 y = e1[e4];
            a0 = fmaf(x.x, w[4 * e4 + 0], a0);
            a1 = fmaf(y.x, w[4 * e4 + 0], a1);
            a0 = fmaf(x.y, w[4 * e4 + 1], a0);
            a1 = fmaf(y.y, w[4 * e4 + 1], a1);
            a0 = fmaf(x.z, w[4 * e4 + 2], a0);
            a1 = fmaf(y.z, w[4 * e4 + 2], a1);
            a0 = fmaf(x.w, w[4 * e4 + 3], a0);
            a1 = fmaf(y.w, w[4 * e4 + 3], a1);
        }
        Pd[(size_t)v * 192 + g] = a0;
        if (v1ok) Pd[(size_t)(v + 1) * 192 + g] = a1;
    }
}

// ---------------- Kernel B: one wave per (dir, batch) sequence; fused mean/max pooling ----------------
// Single wave64 per block => lockstep, no barriers needed for the h LDS broadcast.
//
// The xg prefetch is done with INLINE-ASM global_load_dword into a depth-8 ring of named
// registers, with a hand-counted `s_waitcnt vmcnt(21)` (24 loads in flight, retire oldest 3).
// Rationale: hipcc does not rename a prefetch load onto the register consumed N iterations
// later -- it keeps a temporary and drains vmcnt in the SAME iteration the load was issued,
// collapsing any source-level ring to depth 1 (measured: 990 cyc/step ~= compute + full
// random-access latency into the 77MB table). Asm loads are untracked by the compiler's
// waitcnt insertion, so the counted wait 8 steps downstream is preserved.
// sched_barrier(0) after the wait per rule: compiler otherwise hoists register-only
// consumers above an inline-asm s_waitcnt.
__global__ __launch_bounds__(64, 1) void gru_seq(
    const int* __restrict__ tokens,
    const float* __restrict__ whh_f, const float* __restrict__ bhh_f,
    const float* __restrict__ whh_b, const float* __restrict__ bhh_b)
{
    const int lane = threadIdx.x;        // hidden unit index
    const int blk = blockIdx.x;          // 0..255
    const int b = blk >> 1;
    const int dir = blk & 1;
    const float* whh = dir ? whh_b : whh_f;
    const float* bhh = dir ? bhh_b : bhh_f;
    const float* Pd = g_P + (size_t)dir * VOCAB * 192;

    __shared__ __align__(16) float h_lds[64];
    __shared__ __align__(16) int tok_lds[TLEN];

    // stage token row (8 KB) once, vectorized: 512 int4 across 64 lanes = 8 iterations
    {
        const int4* src = (const int4*)(tokens + (size_t)b * TLEN);
        int4* dst = (int4*)tok_lds;
        for (int t = lane; t < TLEN / 4; t += 64) dst[t] = src[t];
    }

    // per-lane whh rows (r,z,n) -> 192 VGPRs as v2f
    v2f wr[32], wz[32], wn[32];
    {
        const float* pr = whh + (size_t)(0 + lane) * 64;
        const float* pz = whh + (size_t)(64 + lane) * 64;
        const float* pn = whh + (size_t)(128 + lane) * 64;
#pragma unroll
        for (int k = 0; k < 16; k++) {
            float4 a = *(const float4*)(pr + 4 * k);
            wr[2 * k] = (v2f){a.x, a.y}; wr[2 * k + 1] = (v2f){a.z, a.w};
            float4 c = *(const float4*)(pz + 4 * k);
            wz[2 * k] = (v2f){c.x, c.y}; wz[2 * k + 1] = (v2f){c.z, c.w};
            float4 d = *(const float4*)(pn + 4 * k);
            wn[2 * k] = (v2f){d.x, d.y}; wn[2 * k + 1] = (v2f){d.z, d.w};
        }
    }
    const float br = bhh[lane], bz = bhh[64 + lane], bn = bhh[128 + lane];

    h_lds[lane] = 0.f;
    float h = 0.f, sum = 0.f, mx = -INFINITY;

    // time mapping: step s -> tt = dir ? T-1-s : s (backward dir feeds reversed sequence)
    auto tok_at = [&](int s) -> int {
        int ss = s < TLEN ? s : TLEN - 1;        // clamp for tail prefetches (values unused)
        return tok_lds[dir ? (TLEN - 1 - ss) : ss];
    };

    // depth-8 xg ring: 24 named registers, defined ONLY by asm loads
    float xr0, xz0, xn0, xr1, xz1, xn1, xr2, xz2, xn2, xr3, xz3, xn3;
    float xr4, xz4, xn4, xr5, xz5, xn5, xr6, xz6, xn6, xr7, xz7, xn7;

#define GRU_PRE(SL, D) do {                                                        \
        const float* rd_ = Pd + (size_t)tok_at(D) * 192;                           \
        asm volatile("global_load_dword %0, %1, off" : "=v"(xr##SL) : "v"(rd_ + lane));       \
        asm volatile("global_load_dword %0, %1, off" : "=v"(xz##SL) : "v"(rd_ + 64 + lane));  \
        asm volatile("global_load_dword %0, %1, off" : "=v"(xn##SL) : "v"(rd_ + 128 + lane)); \
    } while (0)

    GRU_PRE(0, 0); GRU_PRE(1, 1); GRU_PRE(2, 2); GRU_PRE(3, 3);
    GRU_PRE(4, 4); GRU_PRE(5, 5); GRU_PRE(6, 6); GRU_PRE(7, 7);

#define GRU_STEP(SL, SB) do {                                                      \
        const int tN_ = tok_at((SB) + 8);                                          \
        v2f ar0 = {0.f, 0.f}, ar1 = {0.f, 0.f};                                    \
        v2f az0 = {0.f, 0.f}, az1 = {0.f, 0.f};                                    \
        v2f an0 = {0.f, 0.f}, an1 = {0.f, 0.f};                                    \
        _Pragma("unroll")                                                          \
        for (int k = 0; k < 16; k++) {                                             \
            float4 h4 = *(const float4*)(h_lds + 4 * k);                           \
            v2f h01 = {h4.x, h4.y}, h23 = {h4.z, h4.w};                            \
            ar0 = __builtin_elementwise_fma(h01, wr[2 * k], ar0);                  \
            az0 = __builtin_elementwise_fma(h01, wz[2 * k], az0);                  \
            an0 = __builtin_elementwise_fma(h01, wn[2 * k], an0);                  \
            ar1 = __builtin_elementwise_fma(h23, wr[2 * k + 1], ar1);              \
            az1 = __builtin_elementwise_fma(h23, wz[2 * k + 1], az1);              \
            an1 = __builtin_elementwise_fma(h23, wn[2 * k + 1], an1);              \
        }                                                                          \
        float hr = (ar0.x + ar0.y) + (ar1.x + ar1.y);                              \
        float hz = (az0.x + az0.y) + (az1.x + az1.y);                              \
        float hn = (an0.x + an0.y) + (an1.x + an1.y);                              \
        asm volatile("s_waitcnt vmcnt(21)" ::: "memory");                          \
        __builtin_amdgcn_sched_barrier(0);                                         \
        float r_ = fsigmoid(xr##SL + hr + br);                                     \
        float z_ = fsigmoid(xz##SL + hz + bz);                                     \
        float n_ = ftanh(xn##SL + r_ * (hn + bn));                                 \
        h = fmaf(z_, h - n_, n_);              /* (1-z)*n + z*h */                 \
        sum += h;                                                                  \
        mx = fmaxf(mx, h);                                                         \
        h_lds[lane] = h;   /* single-wave lockstep: no barrier needed */           \
        const float* rp_ = Pd + (size_t)tN_ * 192;                                 \
        asm volatile("global_load_dword %0, %1, off" : "=v"(xr##SL) : "v"(rp_ + lane));       \
        asm volatile("global_load_dword %0, %1, off" : "=v"(xz##SL) : "v"(rp_ + 64 + lane));  \
        asm volatile("global_load_dword %0, %1, off" : "=v"(xn##SL) : "v"(rp_ + 128 + lane)); \
    } while (0)

    for (int s = 0; s < TLEN; s += 8) {
        GRU_STEP(0, s + 0);
        GRU_STEP(1, s + 1);
        GRU_STEP(2, s + 2);
        GRU_STEP(3, s + 3);
        GRU_STEP(4, s + 4);
        GRU_STEP(5, s + 5);
        GRU_STEP(6, s + 6);
        GRU_STEP(7, s + 7);
    }
    // drain the 24 tail prefetches (clamped addresses, values dead) before wave end
    asm volatile("s_waitcnt vmcnt(0)" ::: "memory");

    // feats layout [b][256]: [mean_f | mean_b | max_f | max_b]
    g_feats[b * 256 + dir * 64 + lane] = sum * (1.f / TLEN);
    g_feats[b * 256 + 128 + dir * 64 + lane] = mx;
#undef GRU_PRE
#undef GRU_STEP
}

// ---------------- Kernel C: classifier  out = W2 @ gelu(W1 @ feats + b1) + b2 ----------------
__global__ __launch_bounds__(64) void classifier(
    const float* __restrict__ w1, const float* __restrict__ b1,
    const float* __restrict__ w2, const float* __restrict__ b2,
    float* __restrict__ out)
{
    const int b = blockIdx.x;
    const int i = threadIdx.x;
    __shared__ float f[256];
    __shared__ float hid[64];
    for (int c = i; c < 256; c += 64) f[c] = g_feats[b * 256 + c];
    __syncthreads();

    float acc = b1[i];
    const float* wrow = w1 + (size_t)i * 256;
#pragma unroll 16
    for (int c = 0; c < 256; c++) acc = fmaf(f[c], wrow[c], acc);
    // exact GELU: x * 0.5 * (1 + erf(x/sqrt(2)))
    hid[i] = acc * 0.5f * (1.f + erff(acc * 0.70710678118654752f));
    __syncthreads();

    if (i < NCLS) {
        float o = b2[i];
        const float* w2r = w2 + (size_t)i * 64;
#pragma unroll
        for (int j = 0; j < 64; j++) o = fmaf(hid[j], w2r[j], o);
        out[b * NCLS + i] = o;
    }
}

extern "C" void kernel_launch(void* const* d_in, const int* in_sizes, int n_in,
                              void* d_out, int out_size, void* d_ws, size_t ws_size,
                              hipStream_t stream) {
    const int*   tokens = (const int*)  d_in[0];
    const float* emb    = (const float*)d_in[1];
    const float* wih_f  = (const float*)d_in[2];
    const float* whh_f  = (const float*)d_in[3];
    const float* bih_f  = (const float*)d_in[4];
    const float* bhh_f  = (const float*)d_in[5];
    const float* wih_b  = (const float*)d_in[6];
    const float* whh_b  = (const float*)d_in[7];
    const float* bih_b  = (const float*)d_in[8];
    const float* bhh_b  = (const float*)d_in[9];
    const float* w1     = (const float*)d_in[10];
    const float* b1     = (const float*)d_in[11];
    const float* w2     = (const float*)d_in[12];
    const float* b2     = (const float*)d_in[13];
    float* out = (float*)d_out;

    precompute_P<<<4096, 384, 0, stream>>>(emb, wih_f, bih_f, wih_b, bih_b);
    gru_seq<<<2 * BATCH, 64, 0, stream>>>(tokens, whh_f, bhh_f, whh_b, bhh_b);
    classifier<<<BATCH, 64, 0, stream>>>(w1, b1, w2, b2, out);
}

// Round 4
// 950.142 us; speedup vs baseline: 1.4718x; 1.4718x over previous
//
#include <hip/hip_runtime.h>
#include <hip/hip_bf16.h>
#include <math.h>

#define VOCAB 50257
#define NCLS 20
#define EDIM 64
#define HDIM 64
#define BATCH 128
#define TLEN 2048

typedef float v2f __attribute__((ext_vector_type(2)));

// Static device scratch: no dependence on ws_size, graph-capture safe.
__device__ float g_P[(size_t)2 * VOCAB * 192];   // 77.2 MB, input-projected vocab table (bias folded)
__device__ float g_feats[BATCH * 256];           // pooled features

__device__ __forceinline__ float fast_rcp(float x) { return __builtin_amdgcn_rcpf(x); }

__device__ __forceinline__ float fsigmoid(float x) {
    // 1/(1+exp(-x)); saturates correctly at +-inf
    return fast_rcp(1.f + __expf(-x));
}
__device__ __forceinline__ float ftanh(float x) {
    // 1 - 2/(exp(2x)+1); saturates correctly at +-inf
    float e = __expf(2.f * x);
    return 1.f - 2.f * fast_rcp(e + 1.f);
}

// ---------------- Kernel A: P[dir][v][g] = dot(emb[v], wih[dir][g]) + bih[dir][g] ----------------
__global__ __launch_bounds__(384) void precompute_P(
    const float* __restrict__ emb,
    const float* __restrict__ wih_f, const float* __restrict__ bih_f,
    const float* __restrict__ wih_b, const float* __restrict__ bih_b)
{
    const int t = threadIdx.x;          // 0..383 ; waves are uniform in (dir), contiguous in g
    const int dir = t / 192;
    const int g = t % 192;
    const float* wih = dir ? wih_b : wih_f;
    const float* bih = dir ? bih_b : bih_f;

    float w[64];
#pragma unroll
    for (int e = 0; e < 64; e += 4) {
        float4 v = *(const float4*)(wih + (size_t)g * 64 + e);
        w[e] = v.x; w[e + 1] = v.y; w[e + 2] = v.z; w[e + 3] = v.w;
    }
    const float bias = bih[g];
    float* Pd = g_P + (size_t)dir * VOCAB * 192;

    for (int v = blockIdx.x * 2; v < VOCAB; v += gridDim.x * 2) {
        const int v1ok = (v + 1 < VOCAB);
        const float4* e0 = (const float4*)(emb + (size_t)v * 64);            // wave-uniform -> scalar loads
        const float4* e1 = (const float4*)(emb + (size_t)(v1ok ? v + 1 : v) * 64);
        float a0 = bias, a1 = bias;
#pragma unroll
        for (int e4 = 0; e4 < 16; e4++) {
            float4 x = e0[e4];
            float4 y = e1[e4];
            a0 = fmaf(x.x, w[4 * e4 + 0], a0);
            a1 = fmaf(y.x, w[4 * e4 + 0], a1);
            a0 = fmaf(x.y, w[4 * e4 + 1], a0);
            a1 = fmaf(y.y, w[4 * e4 + 1], a1);
            a0 = fmaf(x.z, w[4 * e4 + 2], a0);
            a1 = fmaf(y.z, w[4 * e4 + 2], a1);
            a0 = fmaf(x.w, w[4 * e4 + 3], a0);
            a1 = fmaf(y.w, w[4 * e4 + 3], a1);
        }
        Pd[(size_t)v * 192 + g] = a0;
        if (v1ok) Pd[(size_t)(v + 1) * 192 + g] = a1;
    }
}

// ---------------- Kernel B: one wave per (dir, batch) sequence; fused mean/max pooling ----------------
// Single wave64 per block => lockstep, no barriers needed for the h LDS broadcast.
//
// KEY: amdgpu_waves_per_eu(1,1) raises the register-allocator budget to a full wave so the
// 192-VGPR whh weight arrays (plus the prefetch ring) are truly register/AGPR-resident.
// Previous rounds reported VGPR_Count=128-132 -- the weights were spilled/rematerialized
// through memory every step, and the compiler's own vmcnt waits for those hidden loads
// drained the prefetch pipeline (counted waits can't see past compiler vmem). AGPR overflow
// (v_accvgpr_*) is register-register and vmcnt-free, so loop vmem is gone by construction.
//
// xg prefetch: depth-4 ring of named regs defined only by inline-asm global_load_dword.
// Counted wait `s_waitcnt vmcnt(9)` (12 in flight, retire the oldest slot's 3) is tied to
// the slot registers via "+v" constraints: consumers data-depend on the wait (cannot hoist
// above it), and no sched_barrier is needed, leaving the scheduler free elsewhere.
// Safety: the slot being consumed always holds the OLDEST outstanding vmem ops, so the
// counted wait can over-wait but never under-wait, even if stray vmem appears.
__global__ __launch_bounds__(64, 1) __attribute__((amdgpu_waves_per_eu(1, 1)))
void gru_seq(
    const int* __restrict__ tokens,
    const float* __restrict__ whh_f, const float* __restrict__ bhh_f,
    const float* __restrict__ whh_b, const float* __restrict__ bhh_b)
{
    const int lane = threadIdx.x;        // hidden unit index
    const int blk = blockIdx.x;          // 0..255
    const int b = blk >> 1;
    const int dir = blk & 1;
    const float* whh = dir ? whh_b : whh_f;
    const float* bhh = dir ? bhh_b : bhh_f;
    const float* Pd = g_P + (size_t)dir * VOCAB * 192;

    __shared__ __align__(16) float h_lds[64];
    __shared__ __align__(16) int tok_lds[TLEN];

    // stage token row (8 KB) once, vectorized
    {
        const int4* src = (const int4*)(tokens + (size_t)b * TLEN);
        int4* dst = (int4*)tok_lds;
        for (int t = lane; t < TLEN / 4; t += 64) dst[t] = src[t];
    }

    // per-lane whh rows (r,z,n) -> 192 regs as v2f
    v2f wr[32], wz[32], wn[32];
    {
        const float* pr = whh + (size_t)(0 + lane) * 64;
        const float* pz = whh + (size_t)(64 + lane) * 64;
        const float* pn = whh + (size_t)(128 + lane) * 64;
#pragma unroll
        for (int k = 0; k < 16; k++) {
            float4 a = *(const float4*)(pr + 4 * k);
            wr[2 * k] = (v2f){a.x, a.y}; wr[2 * k + 1] = (v2f){a.z, a.w};
            float4 c = *(const float4*)(pz + 4 * k);
            wz[2 * k] = (v2f){c.x, c.y}; wz[2 * k + 1] = (v2f){c.z, c.w};
            float4 d = *(const float4*)(pn + 4 * k);
            wn[2 * k] = (v2f){d.x, d.y}; wn[2 * k + 1] = (v2f){d.z, d.w};
        }
    }
    const float br = bhh[lane], bz = bhh[64 + lane], bn = bhh[128 + lane];

    h_lds[lane] = 0.f;
    float h = 0.f, sum = 0.f, mx = -INFINITY;

    // time mapping: step s -> tt = dir ? T-1-s : s (backward dir feeds reversed sequence)
    auto tok_at = [&](int s) -> int {
        int ss = s < TLEN ? s : TLEN - 1;        // clamp for tail prefetches (values unused)
        return tok_lds[dir ? (TLEN - 1 - ss) : ss];
    };

    // depth-4 xg ring: 12 named registers, defined ONLY by asm loads
    float xr0, xz0, xn0, xr1, xz1, xn1, xr2, xz2, xn2, xr3, xz3, xn3;

#define GRU_PRE(SL, D) do {                                                        \
        const float* rd_ = Pd + (size_t)tok_at(D) * 192;                           \
        asm volatile("global_load_dword %0, %1, off" : "=v"(xr##SL) : "v"(rd_ + lane));       \
        asm volatile("global_load_dword %0, %1, off" : "=v"(xz##SL) : "v"(rd_ + 64 + lane));  \
        asm volatile("global_load_dword %0, %1, off" : "=v"(xn##SL) : "v"(rd_ + 128 + lane)); \
    } while (0)

    GRU_PRE(0, 0); GRU_PRE(1, 1); GRU_PRE(2, 2); GRU_PRE(3, 3);

#define GRU_STEP(SL, SB) do {                                                      \
        const int tN_ = tok_at((SB) + 4);                                          \
        v2f ar0 = {0.f, 0.f}, ar1 = {0.f, 0.f};                                    \
        v2f az0 = {0.f, 0.f}, az1 = {0.f, 0.f};                                    \
        v2f an0 = {0.f, 0.f}, an1 = {0.f, 0.f};                                    \
        _Pragma("unroll")                                                          \
        for (int k = 0; k < 16; k++) {                                             \
            float4 h4 = *(const float4*)(h_lds + 4 * k);                           \
            v2f h01 = {h4.x, h4.y}, h23 = {h4.z, h4.w};                            \
            ar0 = __builtin_elementwise_fma(h01, wr[2 * k], ar0);                  \
            az0 = __builtin_elementwise_fma(h01, wz[2 * k], az0);                  \
            an0 = __builtin_elementwise_fma(h01, wn[2 * k], an0);                  \
            ar1 = __builtin_elementwise_fma(h23, wr[2 * k + 1], ar1);              \
            az1 = __builtin_elementwise_fma(h23, wz[2 * k + 1], az1);              \
            an1 = __builtin_elementwise_fma(h23, wn[2 * k + 1], an1);              \
        }                                                                          \
        float hr = (ar0.x + ar0.y) + (ar1.x + ar1.y);                              \
        float hz = (az0.x + az0.y) + (az1.x + az1.y);                              \
        float hn = (an0.x + an0.y) + (an1.x + an1.y);                              \
        /* retire the oldest slot's 3 loads; consumers depend on the tied regs */  \
        asm volatile("s_waitcnt vmcnt(9)"                                          \
                     : "+v"(xr##SL), "+v"(xz##SL), "+v"(xn##SL));                  \
        float r_ = fsigmoid(xr##SL + hr + br);                                     \
        float z_ = fsigmoid(xz##SL + hz + bz);                                     \
        float n_ = ftanh(xn##SL + r_ * (hn + bn));                                 \
        h = fmaf(z_, h - n_, n_);              /* (1-z)*n + z*h */                 \
        sum += h;                                                                  \
        mx = fmaxf(mx, h);                                                         \
        h_lds[lane] = h;   /* single-wave lockstep: no barrier needed */           \
        const float* rp_ = Pd + (size_t)tN_ * 192;                                 \
        asm volatile("global_load_dword %0, %1, off" : "=v"(xr##SL) : "v"(rp_ + lane));       \
        asm volatile("global_load_dword %0, %1, off" : "=v"(xz##SL) : "v"(rp_ + 64 + lane));  \
        asm volatile("global_load_dword %0, %1, off" : "=v"(xn##SL) : "v"(rp_ + 128 + lane)); \
    } while (0)

    for (int s = 0; s < TLEN; s += 4) {
        GRU_STEP(0, s + 0);
        GRU_STEP(1, s + 1);
        GRU_STEP(2, s + 2);
        GRU_STEP(3, s + 3);
    }
    // drain the 12 tail prefetches (clamped addresses, values dead) before wave end
    asm volatile("s_waitcnt vmcnt(0)" ::: "memory");

    // feats layout [b][256]: [mean_f | mean_b | max_f | max_b]
    g_feats[b * 256 + dir * 64 + lane] = sum * (1.f / TLEN);
    g_feats[b * 256 + 128 + dir * 64 + lane] = mx;
#undef GRU_PRE
#undef GRU_STEP
}

// ---------------- Kernel C: classifier  out = W2 @ gelu(W1 @ feats + b1) + b2 ----------------
__global__ __launch_bounds__(64) void classifier(
    const float* __restrict__ w1, const float* __restrict__ b1,
    const float* __restrict__ w2, const float* __restrict__ b2,
    float* __restrict__ out)
{
    const int b = blockIdx.x;
    const int i = threadIdx.x;
    __shared__ float f[256];
    __shared__ float hid[64];
    for (int c = i; c < 256; c += 64) f[c] = g_feats[b * 256 + c];
    __syncthreads();

    float acc = b1[i];
    const float* wrow = w1 + (size_t)i * 256;
#pragma unroll 16
    for (int c = 0; c < 256; c++) acc = fmaf(f[c], wrow[c], acc);
    // exact GELU: x * 0.5 * (1 + erf(x/sqrt(2)))
    hid[i] = acc * 0.5f * (1.f + erff(acc * 0.70710678118654752f));
    __syncthreads();

    if (i < NCLS) {
        float o = b2[i];
        const float* w2r = w2 + (size_t)i * 64;
#pragma unroll
        for (int j = 0; j < 64; j++) o = fmaf(hid[j], w2r[j], o);
        out[b * NCLS + i] = o;
    }
}

extern "C" void kernel_launch(void* const* d_in, const int* in_sizes, int n_in,
                              void* d_out, int out_size, void* d_ws, size_t ws_size,
                              hipStream_t stream) {
    const int*   tokens = (const int*)  d_in[0];
    const float* emb    = (const float*)d_in[1];
    const float* wih_f  = (const float*)d_in[2];
    const float* whh_f  = (const float*)d_in[3];
    const float* bih_f  = (const float*)d_in[4];
    const float* bhh_f  = (const float*)d_in[5];
    const float* wih_b  = (const float*)d_in[6];
    const float* whh_b  = (const float*)d_in[7];
    const float* bih_b  = (const float*)d_in[8];
    const float* bhh_b  = (const float*)d_in[9];
    const float* w1     = (const float*)d_in[10];
    const float* b1     = (const float*)d_in[11];
    const float* w2     = (const float*)d_in[12];
    const float* b2     = (const float*)d_in[13];
    float* out = (float*)d_out;

    precompute_P<<<4096, 384, 0, stream>>>(emb, wih_f, bih_f, wih_b, bih_b);
    gru_seq<<<2 * BATCH, 64, 0, stream>>>(tokens, whh_f, bhh_f, whh_b, bhh_b);
    classifier<<<BATCH, 64, 0, stream>>>(w1, b1, w2, b2, out);
}